// Round 3
// baseline (613.461 us; speedup 1.0000x reference)
//
#include <hip/hip_runtime.h>
#include <math.h>

// B=262144, N=1e6, R=64, H=128. Outputs: logits [B,2] then loss scalar (f32).
//
// R2 post-mortem: dur 606us = ~465us harness reset floor (2GB ws poison @301us
// + 512MB Wx restore @~158us) + ~141us controllable. 141us for 268MB of random
// 512B gathers = ~2TB/s — latency-bound, not BW-bound. This round: break the
// index->gather dependency chain (LDS index preload), unroll x2 for 6 gathers
// in flight per half-wave, 8192 blocks, coalesced logit stores via LDS.

#define H_DIM 128
#define ROWS_PER_BLOCK 32

__device__ __forceinline__ float4 reg4(float4 w) {
    // s*(1-s), s = sigmoid(clamp(w,-6,6))
    float4 c;
    float v0 = fminf(6.0f, fmaxf(-6.0f, w.x));
    float v1 = fminf(6.0f, fmaxf(-6.0f, w.y));
    float v2 = fminf(6.0f, fmaxf(-6.0f, w.z));
    float v3 = fminf(6.0f, fmaxf(-6.0f, w.w));
    float s0 = 1.0f / (1.0f + __expf(-v0));
    float s1 = 1.0f / (1.0f + __expf(-v1));
    float s2 = 1.0f / (1.0f + __expf(-v2));
    float s3 = 1.0f / (1.0f + __expf(-v3));
    c.x = s0 * (1.0f - s0); c.y = s1 * (1.0f - s1);
    c.z = s2 * (1.0f - s2); c.w = s3 * (1.0f - s3);
    return c;
}

__device__ __forceinline__ float dot3(float4 a, float4 b, float4 c) {
    return a.x * b.x * c.x + a.y * b.y * c.y + a.z * b.z * c.z + a.w * b.w * c.w;
}

__global__ __launch_bounds__(256) void fused_kernel(
    const int* __restrict__ x, const int* __restrict__ y,
    const int* __restrict__ r, const int* __restrict__ l,
    const float* __restrict__ Wx, const float* __restrict__ Wr,
    float* __restrict__ logits, float* __restrict__ partials, int B)
{
    const int group = threadIdx.x >> 5;   // 0..7, half-wave per row
    const int lane  = threadIdx.x & 31;
    const int base  = blockIdx.x * ROWS_PER_BLOCK;

    __shared__ int   sx[ROWS_PER_BLOCK], sy[ROWS_PER_BLOCK], sr[ROWS_PER_BLOCK], sl[ROWS_PER_BLOCK];
    __shared__ float slog[ROWS_PER_BLOCK * 2];
    __shared__ float sloss[8];

    // --- coalesced index preload: 4 half-waves each grab one 128B segment ---
    {
        const int t = threadIdx.x;
        if (t < 128) {
            const int w = t >> 5, i = t & 31, gidx = base + i;
            const bool ok = gidx < B;
            if      (w == 0) sx[i] = ok ? x[gidx] : 0;
            else if (w == 1) sy[i] = ok ? y[gidx] : 0;
            else if (w == 2) sr[i] = ok ? r[gidx] : 0;
            else             sl[i] = ok ? l[gidx] : 0;
        }
    }
    __syncthreads();

    float lossacc = 0.0f;
    const int nvalid = min(ROWS_PER_BLOCK, B - base);  // 32 in the common case

    #pragma unroll
    for (int s = 0; s < 4; s += 2) {
        const int i0 = s * 8 + group;
        const int i1 = i0 + 8;

        // indices from LDS (no global latency in the chain)
        const int x0 = sx[i0], y0 = sy[i0], r0 = sr[i0];
        const int x1 = sx[i1], y1 = sy[i1], r1 = sr[i1];

        // 6 independent 512B gathers in flight
        const float4 a0 = *(const float4*)(Wx + (size_t)x0 * H_DIM + lane * 4);
        const float4 b0 = *(const float4*)(Wx + (size_t)y0 * H_DIM + lane * 4);
        const float4 w0 = *(const float4*)(Wr + (size_t)r0 * H_DIM + lane * 4);
        const float4 a1 = *(const float4*)(Wx + (size_t)x1 * H_DIM + lane * 4);
        const float4 b1 = *(const float4*)(Wx + (size_t)y1 * H_DIM + lane * 4);
        const float4 w1 = *(const float4*)(Wr + (size_t)r1 * H_DIM + lane * 4);

        float d0 = dot3(a0, b0, reg4(w0));
        float d1 = dot3(a1, b1, reg4(w1));
        #pragma unroll
        for (int off = 16; off > 0; off >>= 1) {
            d0 += __shfl_xor(d0, off, 64);
            d1 += __shfl_xor(d1, off, 64);
        }

        if (lane == 0) {
            float p0 = 1.0f / (1.0f + __expf(-d0));
            float p1 = 1.0f / (1.0f + __expf(-d1));
            float q0 = 1.0f - p0, q1 = 1.0f - p1;
            slog[i0 * 2] = p0; slog[i0 * 2 + 1] = q0;
            slog[i1 * 2] = p1; slog[i1 * 2 + 1] = q1;
            // CE on logits [p,q]
            float lse0 = __logf(__expf(p0) + __expf(q0));
            float lse1 = __logf(__expf(p1) + __expf(q1));
            if (i0 < nvalid) lossacc += lse0 - (sl[i0] == 0 ? p0 : q0);
            if (i1 < nvalid) lossacc += lse1 - (sl[i1] == 0 ? p1 : q1);
        }
    }

    if (lane == 0) sloss[group] = lossacc;
    __syncthreads();

    // coalesced logit store: 64 threads, one 256B segment
    {
        const int t = threadIdx.x;
        if (t < ROWS_PER_BLOCK * 2 && (base + (t >> 1)) < B)
            logits[(size_t)base * 2 + t] = slog[t];
    }
    if (threadIdx.x == 0) {
        float s = 0.0f;
        #pragma unroll
        for (int gi = 0; gi < 8; ++gi) s += sloss[gi];
        partials[blockIdx.x] = s;
    }
}

__global__ __launch_bounds__(256) void reduce_kernel(
    const float* __restrict__ partials, int n, float* __restrict__ out, double invB)
{
    __shared__ double sd[256];
    double acc = 0.0;
    for (int i = threadIdx.x; i < n; i += 256) acc += (double)partials[i];
    sd[threadIdx.x] = acc;
    __syncthreads();
    for (int s = 128; s > 0; s >>= 1) {
        if ((int)threadIdx.x < s) sd[threadIdx.x] += sd[threadIdx.x + s];
        __syncthreads();
    }
    if (threadIdx.x == 0) *out = (float)(sd[0] * invB);
}

extern "C" void kernel_launch(void* const* d_in, const int* in_sizes, int n_in,
                              void* d_out, int out_size, void* d_ws, size_t ws_size,
                              hipStream_t stream) {
    const int*   x  = (const int*)d_in[0];
    const int*   y  = (const int*)d_in[1];
    const int*   r  = (const int*)d_in[2];
    const int*   l  = (const int*)d_in[3];
    const float* Wx = (const float*)d_in[4];
    const float* Wr = (const float*)d_in[5];

    const int B = in_sizes[0];

    float* logits   = (float*)d_out;            // [B,2]
    float* loss_out = logits + (size_t)B * 2;   // scalar

    float* partials = (float*)d_ws;
    const int nblk = (B + ROWS_PER_BLOCK - 1) / ROWS_PER_BLOCK;  // 8192

    fused_kernel<<<nblk, 256, 0, stream>>>(x, y, r, l, Wx, Wr, logits, partials, B);
    reduce_kernel<<<1, 256, 0, stream>>>(partials, nblk, loss_out, 1.0 / (double)B);
}